// Round 7
// baseline (322.305 us; speedup 1.0000x reference)
//
#include <hip/hip_runtime.h>
#include <hip/hip_bf16.h>
#include <cstdint>
#include <cstddef>

typedef unsigned short u16;
typedef unsigned int u32;
using f32x4  = __attribute__((ext_vector_type(4))) float;
using bf16x8 = __attribute__((ext_vector_type(8))) short;

__device__ __forceinline__ u16 f2bf(float f) {
    u32 u = __builtin_bit_cast(u32, f);
    u32 r = u + 0x7fffu + ((u >> 16) & 1u);
    return (u16)(r >> 16);
}

// async global->LDS, 16B per lane; LDS dest = wave-uniform base + lane*16 (linear!)
__device__ __forceinline__ void gload16(const u16* g, u16* l) {
    __builtin_amdgcn_global_load_lds(
        (const __attribute__((address_space(1))) void*)g,
        (__attribute__((address_space(3))) void*)l,
        16, 0, 0);
}

// ---------------- fp32 -> bf16 elementwise convert (vectorized) ----------------
__global__ void k_convert(const float* __restrict__ src, u16* __restrict__ dst, int n4) {
    int i = blockIdx.x * blockDim.x + threadIdx.x;
    int stride = gridDim.x * blockDim.x;
    for (; i < n4; i += stride) {
        float4 v = ((const float4*)src)[i];
        ushort4 o;
        o.x = f2bf(v.x); o.y = f2bf(v.y); o.z = f2bf(v.z); o.w = f2bf(v.w);
        ((ushort4*)dst)[i] = o;
    }
}

// ---------------- fp32 [K][N] -> bf16 [N][K] tiled transpose-convert ----------------
__global__ void k_tconv(const float* __restrict__ src, u16* __restrict__ dst, int K, int N) {
    __shared__ float tile[32][33];
    int nb = blockIdx.x * 32, kb = blockIdx.y * 32;
    int tx = threadIdx.x, ty = threadIdx.y;  // 32 x 8
    #pragma unroll
    for (int j = 0; j < 32; j += 8)
        tile[ty + j][tx] = src[(size_t)(kb + ty + j) * N + nb + tx];
    __syncthreads();
    #pragma unroll
    for (int j = 0; j < 32; j += 8)
        dst[(size_t)(nb + ty + j) * K + kb + tx] = f2bf(tile[tx][ty + j]);
}

// ---------------- shared 128x128-tile bf16 MFMA mainloop, 2-phase double-buffered ----------------
// T3 minimum 2-phase recipe (verified m230/m248v2): STAGE(next) issued BEFORE compute(cur);
// one vmcnt(0) + raw s_barrier per tile. Staged-load latency overlaps ds_read+MFMA.
__device__ __forceinline__ void gemm128_mainloop(const u16* __restrict__ A,
                                                 const u16* __restrict__ Bt,
                                                 int m0, int n0, f32x4 (&acc)[4][4]) {
    __shared__ __align__(16) u16 As[2][128][32];
    __shared__ __align__(16) u16 Bs[2][128][32];
    const int t = threadIdx.x;
    const int lane = t & 63, wave = t >> 6;
    const int wr = wave >> 1, wc = wave & 1;
    const int g = lane >> 4, lr = lane & 15;

    #pragma unroll
    for (int mi = 0; mi < 4; mi++)
        #pragma unroll
        for (int ni = 0; ni < 4; ni++)
            acc[mi][ni] = (f32x4){0.f, 0.f, 0.f, 0.f};

    const int q0 = wave * 128 + lane;      // 16B chunk ids (linear LDS byte = q*16)
    const int q1 = q0 + 64;
    const int r0 = q0 >> 2, c0 = (q0 & 3) * 8;
    const int r1 = q1 >> 2, c1 = (q1 & 3) * 8;
    u16* lA0 = &As[0][0][0] + wave * 1024;  // wave-uniform bases
    u16* lA1 = &As[1][0][0] + wave * 1024;
    u16* lB0 = &Bs[0][0][0] + wave * 1024;
    u16* lB1 = &Bs[1][0][0] + wave * 1024;
    const u16* gA0 = A  + (size_t)(m0 + r0) * 1024 + c0;
    const u16* gA1 = A  + (size_t)(m0 + r1) * 1024 + c1;
    const u16* gB0 = Bt + (size_t)(n0 + r0) * 1024 + c0;
    const u16* gB1 = Bt + (size_t)(n0 + r1) * 1024 + c1;

    auto STAGE = [&](u16* la, u16* lb, int kt) {
        gload16(gA0 + kt, la);
        gload16(gA1 + kt, la + 512);
        gload16(gB0 + kt, lb);
        gload16(gB1 + kt, lb + 512);
    };
    auto COMPUTE = [&](const u16 (*Asb)[32], const u16 (*Bsb)[32]) {
        bf16x8 af[4], bfr[4];
        #pragma unroll
        for (int mi = 0; mi < 4; mi++)
            af[mi] = *(const bf16x8*)&Asb[wr * 64 + mi * 16 + lr][g * 8];
        #pragma unroll
        for (int ni = 0; ni < 4; ni++)
            bfr[ni] = *(const bf16x8*)&Bsb[wc * 64 + ni * 16 + lr][g * 8];
        #pragma unroll
        for (int mi = 0; mi < 4; mi++)
            #pragma unroll
            for (int ni = 0; ni < 4; ni++)
                acc[mi][ni] = __builtin_amdgcn_mfma_f32_16x16x32_bf16(af[mi], bfr[ni], acc[mi][ni], 0, 0, 0);
    };

    // prologue: stage tile 0 into buf0
    STAGE(lA0, lB0, 0);
    asm volatile("s_waitcnt vmcnt(0)" ::: "memory");
    __builtin_amdgcn_s_barrier();

    for (int kt = 0; kt < 1024; kt += 64) {
        // phase 0: compute buf0 (tile kt), prefetch tile kt+32 into buf1
        if (kt + 32 < 1024) STAGE(lA1, lB1, kt + 32);
        COMPUTE(As[0], Bs[0]);
        asm volatile("s_waitcnt vmcnt(0)" ::: "memory");
        __builtin_amdgcn_s_barrier();
        // phase 1: compute buf1 (tile kt+32), prefetch tile kt+64 into buf0
        if (kt + 64 < 1024) STAGE(lA0, lB0, kt + 64);
        COMPUTE(As[1], Bs[1]);
        asm volatile("s_waitcnt vmcnt(0)" ::: "memory");
        __builtin_amdgcn_s_barrier();
    }
}

// ---------------- QKV GEMM: C = X@W + b + lora, scatter to Q (x0.125), K, V^T as bf16 ----------------
__global__ __launch_bounds__(256) void k_gemm_qkv(const u16* __restrict__ Xb, const u16* __restrict__ Wab,
                                                  const float* __restrict__ lora, const float* __restrict__ b_attn,
                                                  u16* __restrict__ Qb, u16* __restrict__ Kb, u16* __restrict__ Vt) {
    f32x4 acc[4][4];
    const int m0 = blockIdx.y * 128, n0 = blockIdx.x * 128;
    gemm128_mainloop(Xb, Wab, m0, n0, acc);
    const int lane = threadIdx.x & 63, wave = threadIdx.x >> 6;
    const int wr = wave >> 1, wc = wave & 1, g = lane >> 4, lr = lane & 15;
    #pragma unroll
    for (int mi = 0; mi < 4; mi++)
        #pragma unroll
        for (int ni = 0; ni < 4; ni++)
            #pragma unroll
            for (int r = 0; r < 4; r++) {
                int m = m0 + wr * 64 + mi * 16 + g * 4 + r;
                int n = n0 + wc * 64 + ni * 16 + lr;
                float v = acc[mi][ni][r] + b_attn[n] + lora[(size_t)m * 3072 + n];
                int which = n >> 10, rem = n & 1023, h = rem >> 6, hd = rem & 63;
                int b = m >> 11, s = m & 2047;
                size_t idx = ((size_t)(b * 16 + h) * 2048 + s) * 64 + hd;
                if (which == 0)      Qb[idx] = f2bf(v * 0.125f);   // fold 1/sqrt(64), exact pow2
                else if (which == 1) Kb[idx] = f2bf(v);
                else Vt[((size_t)(b * 16 + h) * 64 + hd) * 2048 + s] = f2bf(v);
            }
}

// ---------------- per-KV-tile attention compute for one wave's 16 q-rows ----------------
__device__ __forceinline__ void attn_tile(const u16 (*Ks)[72], const u16 (*Vs)[72], u16 (*Ps)[72],
                                          int g, int lr, int rowq /*q0+wave*16*/, int k0, bool diag,
                                          bf16x8 qf0, bf16x8 qf1,
                                          f32x4 (&accO)[4], float (&m_run)[4], float (&l_run)[4]) {
    // scores: S = (Q*0.125) @ K^T, C-layout col=key(lr), row=q(g*4+r)
    f32x4 sc[4];
    #pragma unroll
    for (int ni = 0; ni < 4; ni++) {
        bf16x8 kf0 = *(const bf16x8*)&Ks[ni * 16 + lr][g * 8];
        bf16x8 kf1 = *(const bf16x8*)&Ks[ni * 16 + lr][32 + g * 8];
        f32x4 z = {0.f, 0.f, 0.f, 0.f};
        z = __builtin_amdgcn_mfma_f32_16x16x32_bf16(qf0, kf0, z, 0, 0, 0);
        z = __builtin_amdgcn_mfma_f32_16x16x32_bf16(qf1, kf1, z, 0, 0, 0);
        sc[ni] = z;
    }
    if (diag) {  // only the diagonal tile needs masking
        #pragma unroll
        for (int ni = 0; ni < 4; ni++)
            #pragma unroll
            for (int r = 0; r < 4; r++)
                if (k0 + ni * 16 + lr > rowq + g * 4 + r) sc[ni][r] = -INFINITY;
    }
    // online softmax: row r lives in the 16 lanes of this lane-group
    #pragma unroll
    for (int r = 0; r < 4; r++) {
        float mx = fmaxf(fmaxf(sc[0][r], sc[1][r]), fmaxf(sc[2][r], sc[3][r]));
        #pragma unroll
        for (int d = 1; d < 16; d <<= 1) mx = fmaxf(mx, __shfl_xor(mx, d, 64));
        float mnew = fmaxf(m_run[r], mx);
        float fsc = __expf(m_run[r] - mnew);   // first tile: exp(-inf)=0
        float ls = 0.f;
        #pragma unroll
        for (int ni = 0; ni < 4; ni++) {
            float p = __expf(sc[ni][r] - mnew);
            sc[ni][r] = p;
            ls += p;
        }
        #pragma unroll
        for (int d = 1; d < 16; d <<= 1) ls += __shfl_xor(ls, d, 64);
        #pragma unroll
        for (int di = 0; di < 4; di++) accO[di][r] *= fsc;
        m_run[r] = mnew;
        l_run[r] = l_run[r] * fsc + ls;
    }
    // P (C-layout) -> LDS (wave-private slice; same-wave DS ops ordered, no barrier)
    #pragma unroll
    for (int ni = 0; ni < 4; ni++)
        #pragma unroll
        for (int r = 0; r < 4; r++)
            Ps[g * 4 + r][ni * 16 + lr] = f2bf(sc[ni][r]);
    // O += P @ V   (A row = q(lr), B col = d(lr), k = key)
    #pragma unroll
    for (int e = 0; e < 2; e++) {
        bf16x8 pa = *(const bf16x8*)&Ps[lr][e * 32 + g * 8];
        #pragma unroll
        for (int di = 0; di < 4; di++) {
            bf16x8 vb = *(const bf16x8*)&Vs[di * 16 + lr][e * 32 + g * 8];
            accO[di] = __builtin_amdgcn_mfma_f32_16x16x32_bf16(pa, vb, accO[di], 0, 0, 0);
        }
    }
}

// ---------------- causal flash attention: paired q-tiles {i, 31-i} per block ----------------
// Uniform 33 tile-computations/block (no tail); K/V staging shared by both q-tiles.
__global__ __launch_bounds__(256) void k_attn(const u16* __restrict__ Qb, const u16* __restrict__ Kb,
                                              const u16* __restrict__ Vt, u16* __restrict__ Ao) {
    __shared__ __align__(16) u16 Ks[64][72];
    __shared__ __align__(16) u16 Vs[64][72];     // Vs[d][key]
    __shared__ __align__(16) u16 Ps[4][16][72];  // per-wave P tile [q][key] (wave-private)
    const int i = blockIdx.x, bh = blockIdx.y;
    const int qtA = i, qtB = 31 - i;             // qtB > qtA always (i < 16)
    const int t = threadIdx.x, wave = t >> 6, lane = t & 63;
    const int g = lane >> 4, lr = lane & 15;
    const size_t bhO = (size_t)bh * (2048 * 64);
    const int q0A = qtA * 64, q0B = qtB * 64;
    const int rowqA = q0A + wave * 16, rowqB = q0B + wave * 16;

    bf16x8 qfA0 = *(const bf16x8*)(Qb + bhO + (size_t)(rowqA + lr) * 64 + g * 8);
    bf16x8 qfA1 = *(const bf16x8*)(Qb + bhO + (size_t)(rowqA + lr) * 64 + 32 + g * 8);
    bf16x8 qfB0 = *(const bf16x8*)(Qb + bhO + (size_t)(rowqB + lr) * 64 + g * 8);
    bf16x8 qfB1 = *(const bf16x8*)(Qb + bhO + (size_t)(rowqB + lr) * 64 + 32 + g * 8);

    f32x4 accA[4], accB[4];
    float mA[4], lA[4], mB[4], lB[4];
    #pragma unroll
    for (int x = 0; x < 4; x++) {
        accA[x] = (f32x4){0.f,0.f,0.f,0.f}; accB[x] = (f32x4){0.f,0.f,0.f,0.f};
        mA[x] = -INFINITY; lA[x] = 0.f; mB[x] = -INFINITY; lB[x] = 0.f;
    }

    const int sr0 = t >> 3,         sj0 = t & 7;
    const int sr1 = (t + 256) >> 3, sj1 = (t + 256) & 7;
    const u16* gK0 = Kb + bhO + (size_t)sr0 * 64 + sj0 * 8;
    const u16* gK1 = Kb + bhO + (size_t)sr1 * 64 + sj1 * 8;
    const u16* gV0 = Vt + bhO + (size_t)sr0 * 2048 + sj0 * 8;
    const u16* gV1 = Vt + bhO + (size_t)sr1 * 2048 + sj1 * 8;

    // prologue: prefetch tile 0 into registers
    uint4 pk0 = *(const uint4*)(gK0);
    uint4 pk1 = *(const uint4*)(gK1);
    uint4 pv0 = *(const uint4*)(gV0);
    uint4 pv1 = *(const uint4*)(gV1);

    for (int kt = 0; kt <= qtB; ++kt) {
        const int k0 = kt * 64;
        __syncthreads();  // previous iteration's LDS reads done before restaging
        *(uint4*)&Ks[sr0][sj0 * 8] = pk0;
        *(uint4*)&Ks[sr1][sj1 * 8] = pk1;
        *(uint4*)&Vs[sr0][sj0 * 8] = pv0;
        *(uint4*)&Vs[sr1][sj1 * 8] = pv1;
        __syncthreads();

        if (kt < qtB) {   // issue next tile's loads now; latency hides under compute
            const size_t kn = (size_t)(k0 + 64);
            pk0 = *(const uint4*)(gK0 + kn * 64);
            pk1 = *(const uint4*)(gK1 + kn * 64);
            pv0 = *(const uint4*)(gV0 + kn);
            pv1 = *(const uint4*)(gV1 + kn);
        }

        if (kt <= qtA)    // tile A active while kt within its causal range
            attn_tile(Ks, Vs, Ps[wave], g, lr, rowqA, k0, kt == qtA, qfA0, qfA1, accA, mA, lA);
        attn_tile(Ks, Vs, Ps[wave], g, lr, rowqB, k0, kt == qtB, qfB0, qfB1, accB, mB, lB);
    }

    const int b = bh >> 4, h = bh & 15;
    #pragma unroll
    for (int di = 0; di < 4; di++)
        #pragma unroll
        for (int r = 0; r < 4; r++) {
            int sA = rowqA + g * 4 + r;
            int sB = rowqB + g * 4 + r;
            Ao[((size_t)(b * 2048 + sA)) * 1024 + h * 64 + di * 16 + lr] = f2bf(accA[di][r] / lA[r]);
            Ao[((size_t)(b * 2048 + sB)) * 1024 + h * 64 + di * 16 + lr] = f2bf(accB[di][r] / lB[r]);
        }
}

// ---------------- output projection: out = Ao @ Wp + b (fp32 out) ----------------
__global__ __launch_bounds__(256) void k_gemm_proj(const u16* __restrict__ Ao, const u16* __restrict__ Wpb,
                                                   const float* __restrict__ b_proj, float* __restrict__ out) {
    f32x4 acc[4][4];
    const int m0 = blockIdx.y * 128, n0 = blockIdx.x * 128;
    gemm128_mainloop(Ao, Wpb, m0, n0, acc);
    const int lane = threadIdx.x & 63, wave = threadIdx.x >> 6;
    const int wr = wave >> 1, wc = wave & 1, g = lane >> 4, lr = lane & 15;
    #pragma unroll
    for (int mi = 0; mi < 4; mi++)
        #pragma unroll
        for (int ni = 0; ni < 4; ni++)
            #pragma unroll
            for (int r = 0; r < 4; r++) {
                int m = m0 + wr * 64 + mi * 16 + g * 4 + r;
                int n = n0 + wc * 64 + ni * 16 + lr;
                out[(size_t)m * 1024 + n] = acc[mi][ni][r] + b_proj[n];
            }
}

extern "C" void kernel_launch(void* const* d_in, const int* in_sizes, int n_in,
                              void* d_out, int out_size, void* d_ws, size_t ws_size,
                              hipStream_t stream) {
    const float* hidden = (const float*)d_in[0];
    const float* lora   = (const float*)d_in[1];
    const float* w_attn = (const float*)d_in[2];
    const float* b_attn = (const float*)d_in[3];
    const float* w_proj = (const float*)d_in[4];
    const float* b_proj = (const float*)d_in[5];
    float* out = (float*)d_out;

    char* ws = (char*)d_ws;
    u16* Xb  = (u16*)(ws + 0x0);        // 4096x1024 bf16 (reused as Ao after QKV GEMM)
    u16* Wab = (u16*)(ws + 0x800000);   // w_attn^T  [3072][1024] bf16
    u16* Wpb = (u16*)(ws + 0xE00000);   // w_proj^T  [1024][1024] bf16
    u16* Qb  = (u16*)(ws + 0x1000000);  // [B,H,S,64] bf16 (pre-scaled by 0.125)
    u16* Kb  = (u16*)(ws + 0x1800000);  // [B,H,S,64] bf16
    u16* Vt  = (u16*)(ws + 0x2000000);  // [B,H,64,S] bf16
    u16* Ao  = Xb;                      // merged attention output [B,S,1024] bf16

    k_convert<<<1024, 256, 0, stream>>>(hidden, Xb, (2 * 2048 * 1024) / 4);
    k_tconv<<<dim3(96, 32), dim3(32, 8), 0, stream>>>(w_attn, Wab, 1024, 3072);
    k_tconv<<<dim3(32, 32), dim3(32, 8), 0, stream>>>(w_proj, Wpb, 1024, 1024);
    k_gemm_qkv<<<dim3(24, 32), 256, 0, stream>>>(Xb, Wab, lora, b_attn, Qb, Kb, Vt);
    k_attn<<<dim3(16, 32), 256, 0, stream>>>(Qb, Kb, Vt, Ao);
    k_gemm_proj<<<dim3(8, 32), 256, 0, stream>>>(Ao, Wpb, b_proj, out);
}

// Round 8
// 317.269 us; speedup vs baseline: 1.0159x; 1.0159x over previous
//
#include <hip/hip_runtime.h>
#include <hip/hip_bf16.h>
#include <cstdint>
#include <cstddef>

typedef unsigned short u16;
typedef unsigned int u32;
using f32x4  = __attribute__((ext_vector_type(4))) float;
using bf16x8 = __attribute__((ext_vector_type(8))) short;

__device__ __forceinline__ u16 f2bf(float f) {
    u32 u = __builtin_bit_cast(u32, f);
    u32 r = u + 0x7fffu + ((u >> 16) & 1u);
    return (u16)(r >> 16);
}

// async global->LDS, 16B per lane; LDS dest = wave-uniform base + lane*16 (linear!)
__device__ __forceinline__ void gload16(const u16* g, u16* l) {
    __builtin_amdgcn_global_load_lds(
        (const __attribute__((address_space(1))) void*)g,
        (__attribute__((address_space(3))) void*)l,
        16, 0, 0);
}

// ---------------- fp32 -> bf16 elementwise convert (vectorized) ----------------
__global__ void k_convert(const float* __restrict__ src, u16* __restrict__ dst, int n4) {
    int i = blockIdx.x * blockDim.x + threadIdx.x;
    int stride = gridDim.x * blockDim.x;
    for (; i < n4; i += stride) {
        float4 v = ((const float4*)src)[i];
        ushort4 o;
        o.x = f2bf(v.x); o.y = f2bf(v.y); o.z = f2bf(v.z); o.w = f2bf(v.w);
        ((ushort4*)dst)[i] = o;
    }
}

// ---------------- fp32 [K][N] -> bf16 [N][K] tiled transpose-convert ----------------
__global__ void k_tconv(const float* __restrict__ src, u16* __restrict__ dst, int K, int N) {
    __shared__ float tile[32][33];
    int nb = blockIdx.x * 32, kb = blockIdx.y * 32;
    int tx = threadIdx.x, ty = threadIdx.y;  // 32 x 8
    #pragma unroll
    for (int j = 0; j < 32; j += 8)
        tile[ty + j][tx] = src[(size_t)(kb + ty + j) * N + nb + tx];
    __syncthreads();
    #pragma unroll
    for (int j = 0; j < 32; j += 8)
        dst[(size_t)(nb + ty + j) * K + kb + tx] = f2bf(tile[tx][ty + j]);
}

// ---------------- shared 128x128-tile bf16 MFMA mainloop, 2-buffer + COUNTED vmcnt (T4) ----------------
// Each STAGE = 4 global_load_lds per wave. FIFO: steady state keeps 8 in flight, waits vmcnt(4)
// (oldest buffer landed) -> one full compute phase of latency cover. Only the final phase drains.
__device__ __forceinline__ void gemm128_mainloop(const u16* __restrict__ A,
                                                 const u16* __restrict__ Bt,
                                                 int m0, int n0, f32x4 (&acc)[4][4]) {
    __shared__ __align__(16) u16 As[2][128][32];
    __shared__ __align__(16) u16 Bs[2][128][32];
    const int t = threadIdx.x;
    const int lane = t & 63, wave = t >> 6;
    const int wr = wave >> 1, wc = wave & 1;
    const int g = lane >> 4, lr = lane & 15;

    #pragma unroll
    for (int mi = 0; mi < 4; mi++)
        #pragma unroll
        for (int ni = 0; ni < 4; ni++)
            acc[mi][ni] = (f32x4){0.f, 0.f, 0.f, 0.f};

    const int q0 = wave * 128 + lane;      // 16B chunk ids (linear LDS byte = q*16)
    const int q1 = q0 + 64;
    const int r0 = q0 >> 2, c0 = (q0 & 3) * 8;
    const int r1 = q1 >> 2, c1 = (q1 & 3) * 8;
    u16* lA0 = &As[0][0][0] + wave * 1024;  // wave-uniform bases
    u16* lA1 = &As[1][0][0] + wave * 1024;
    u16* lB0 = &Bs[0][0][0] + wave * 1024;
    u16* lB1 = &Bs[1][0][0] + wave * 1024;
    const u16* gA0 = A  + (size_t)(m0 + r0) * 1024 + c0;
    const u16* gA1 = A  + (size_t)(m0 + r1) * 1024 + c1;
    const u16* gB0 = Bt + (size_t)(n0 + r0) * 1024 + c0;
    const u16* gB1 = Bt + (size_t)(n0 + r1) * 1024 + c1;

    auto STAGE = [&](u16* la, u16* lb, int kt) {   // 4 global_load_lds per wave
        gload16(gA0 + kt, la);
        gload16(gA1 + kt, la + 512);
        gload16(gB0 + kt, lb);
        gload16(gB1 + kt, lb + 512);
    };
    auto COMPUTE = [&](const u16 (*Asb)[32], const u16 (*Bsb)[32]) {
        bf16x8 af[4], bfr[4];
        #pragma unroll
        for (int mi = 0; mi < 4; mi++)
            af[mi] = *(const bf16x8*)&Asb[wr * 64 + mi * 16 + lr][g * 8];
        #pragma unroll
        for (int ni = 0; ni < 4; ni++)
            bfr[ni] = *(const bf16x8*)&Bsb[wc * 64 + ni * 16 + lr][g * 8];
        #pragma unroll
        for (int mi = 0; mi < 4; mi++)
            #pragma unroll
            for (int ni = 0; ni < 4; ni++)
                acc[mi][ni] = __builtin_amdgcn_mfma_f32_16x16x32_bf16(af[mi], bfr[ni], acc[mi][ni], 0, 0, 0);
    };

    // prologue: 8 loads in flight (b0 older 4, b1 newer 4)
    STAGE(lA0, lB0, 0);
    STAGE(lA1, lB1, 32);

    for (int kt = 0; kt < 1024; kt += 64) {
        // ---- phase 0: consume b0(kt). Oldest 4 must have landed; b1's 4 stay in flight.
        asm volatile("s_waitcnt vmcnt(4)" ::: "memory");
        __builtin_amdgcn_s_barrier();
        COMPUTE(As[0], Bs[0]);
        __builtin_amdgcn_s_barrier();                  // all waves done reading b0
        asm volatile("" ::: "memory");                 // pin DMA issue below the reads
        if (kt + 64 < 1024) {
            STAGE(lA0, lB0, kt + 64);                  // in flight: b1(4) + b0new(4)
            asm volatile("s_waitcnt vmcnt(4)" ::: "memory");   // b1 landed
        } else {
            asm volatile("s_waitcnt vmcnt(0)" ::: "memory");   // tail: drain b1
        }
        // ---- phase 1: consume b1(kt+32)
        __builtin_amdgcn_s_barrier();
        COMPUTE(As[1], Bs[1]);
        __builtin_amdgcn_s_barrier();                  // all waves done reading b1
        asm volatile("" ::: "memory");
        if (kt + 96 < 1024)
            STAGE(lA1, lB1, kt + 96);                  // in flight: b0new(4) + b1new(4)
    }
}

// ---------------- QKV GEMM: C = X@W + b + lora, scatter to Q (x0.125), K, V^T as bf16 ----------------
__global__ __launch_bounds__(256) void k_gemm_qkv(const u16* __restrict__ Xb, const u16* __restrict__ Wab,
                                                  const float* __restrict__ lora, const float* __restrict__ b_attn,
                                                  u16* __restrict__ Qb, u16* __restrict__ Kb, u16* __restrict__ Vt) {
    f32x4 acc[4][4];
    const int m0 = blockIdx.y * 128, n0 = blockIdx.x * 128;
    gemm128_mainloop(Xb, Wab, m0, n0, acc);
    const int lane = threadIdx.x & 63, wave = threadIdx.x >> 6;
    const int wr = wave >> 1, wc = wave & 1, g = lane >> 4, lr = lane & 15;
    #pragma unroll
    for (int mi = 0; mi < 4; mi++)
        #pragma unroll
        for (int ni = 0; ni < 4; ni++)
            #pragma unroll
            for (int r = 0; r < 4; r++) {
                int m = m0 + wr * 64 + mi * 16 + g * 4 + r;
                int n = n0 + wc * 64 + ni * 16 + lr;
                float v = acc[mi][ni][r] + b_attn[n] + lora[(size_t)m * 3072 + n];
                int which = n >> 10, rem = n & 1023, h = rem >> 6, hd = rem & 63;
                int b = m >> 11, s = m & 2047;
                size_t idx = ((size_t)(b * 16 + h) * 2048 + s) * 64 + hd;
                if (which == 0)      Qb[idx] = f2bf(v * 0.125f);   // fold 1/sqrt(64), exact pow2
                else if (which == 1) Kb[idx] = f2bf(v);
                else Vt[((size_t)(b * 16 + h) * 64 + hd) * 2048 + s] = f2bf(v);
            }
}

// ---------------- per-KV-tile attention compute for one wave's 16 q-rows ----------------
__device__ __forceinline__ void attn_tile(const u16 (*Ks)[72], const u16 (*Vs)[72], u16 (*Ps)[72],
                                          int g, int lr, int rowq /*q0+wave*16*/, int k0, bool diag,
                                          bf16x8 qf0, bf16x8 qf1,
                                          f32x4 (&accO)[4], float (&m_run)[4], float (&l_run)[4]) {
    // scores: S = (Q*0.125) @ K^T, C-layout col=key(lr), row=q(g*4+r)
    f32x4 sc[4];
    #pragma unroll
    for (int ni = 0; ni < 4; ni++) {
        bf16x8 kf0 = *(const bf16x8*)&Ks[ni * 16 + lr][g * 8];
        bf16x8 kf1 = *(const bf16x8*)&Ks[ni * 16 + lr][32 + g * 8];
        f32x4 z = {0.f, 0.f, 0.f, 0.f};
        z = __builtin_amdgcn_mfma_f32_16x16x32_bf16(qf0, kf0, z, 0, 0, 0);
        z = __builtin_amdgcn_mfma_f32_16x16x32_bf16(qf1, kf1, z, 0, 0, 0);
        sc[ni] = z;
    }
    if (diag) {  // only the diagonal tile needs masking
        #pragma unroll
        for (int ni = 0; ni < 4; ni++)
            #pragma unroll
            for (int r = 0; r < 4; r++)
                if (k0 + ni * 16 + lr > rowq + g * 4 + r) sc[ni][r] = -INFINITY;
    }
    // online softmax: row r lives in the 16 lanes of this lane-group
    #pragma unroll
    for (int r = 0; r < 4; r++) {
        float mx = fmaxf(fmaxf(sc[0][r], sc[1][r]), fmaxf(sc[2][r], sc[3][r]));
        #pragma unroll
        for (int d = 1; d < 16; d <<= 1) mx = fmaxf(mx, __shfl_xor(mx, d, 64));
        float mnew = fmaxf(m_run[r], mx);
        float fsc = __expf(m_run[r] - mnew);   // first tile: exp(-inf)=0
        float ls = 0.f;
        #pragma unroll
        for (int ni = 0; ni < 4; ni++) {
            float p = __expf(sc[ni][r] - mnew);
            sc[ni][r] = p;
            ls += p;
        }
        #pragma unroll
        for (int d = 1; d < 16; d <<= 1) ls += __shfl_xor(ls, d, 64);
        #pragma unroll
        for (int di = 0; di < 4; di++) accO[di][r] *= fsc;
        m_run[r] = mnew;
        l_run[r] = l_run[r] * fsc + ls;
    }
    // P (C-layout) -> LDS (wave-private slice; same-wave DS ops ordered, no barrier)
    #pragma unroll
    for (int ni = 0; ni < 4; ni++)
        #pragma unroll
        for (int r = 0; r < 4; r++)
            Ps[g * 4 + r][ni * 16 + lr] = f2bf(sc[ni][r]);
    // O += P @ V   (A row = q(lr), B col = d(lr), k = key)
    #pragma unroll
    for (int e = 0; e < 2; e++) {
        bf16x8 pa = *(const bf16x8*)&Ps[lr][e * 32 + g * 8];
        #pragma unroll
        for (int di = 0; di < 4; di++) {
            bf16x8 vb = *(const bf16x8*)&Vs[di * 16 + lr][e * 32 + g * 8];
            accO[di] = __builtin_amdgcn_mfma_f32_16x16x32_bf16(pa, vb, accO[di], 0, 0, 0);
        }
    }
}

// ---------------- causal flash attention: paired q-tiles {i, 31-i} per block ----------------
// Uniform 33 tile-computations/block (no tail); K/V staging shared by both q-tiles.
__global__ __launch_bounds__(256) void k_attn(const u16* __restrict__ Qb, const u16* __restrict__ Kb,
                                              const u16* __restrict__ Vt, u16* __restrict__ Ao) {
    __shared__ __align__(16) u16 Ks[64][72];
    __shared__ __align__(16) u16 Vs[64][72];     // Vs[d][key]
    __shared__ __align__(16) u16 Ps[4][16][72];  // per-wave P tile [q][key] (wave-private)
    const int i = blockIdx.x, bh = blockIdx.y;
    const int qtA = i, qtB = 31 - i;             // qtB > qtA always (i < 16)
    const int t = threadIdx.x, wave = t >> 6, lane = t & 63;
    const int g = lane >> 4, lr = lane & 15;
    const size_t bhO = (size_t)bh * (2048 * 64);
    const int q0A = qtA * 64, q0B = qtB * 64;
    const int rowqA = q0A + wave * 16, rowqB = q0B + wave * 16;

    bf16x8 qfA0 = *(const bf16x8*)(Qb + bhO + (size_t)(rowqA + lr) * 64 + g * 8);
    bf16x8 qfA1 = *(const bf16x8*)(Qb + bhO + (size_t)(rowqA + lr) * 64 + 32 + g * 8);
    bf16x8 qfB0 = *(const bf16x8*)(Qb + bhO + (size_t)(rowqB + lr) * 64 + g * 8);
    bf16x8 qfB1 = *(const bf16x8*)(Qb + bhO + (size_t)(rowqB + lr) * 64 + 32 + g * 8);

    f32x4 accA[4], accB[4];
    float mA[4], lA[4], mB[4], lB[4];
    #pragma unroll
    for (int x = 0; x < 4; x++) {
        accA[x] = (f32x4){0.f,0.f,0.f,0.f}; accB[x] = (f32x4){0.f,0.f,0.f,0.f};
        mA[x] = -INFINITY; lA[x] = 0.f; mB[x] = -INFINITY; lB[x] = 0.f;
    }

    const int sr0 = t >> 3,         sj0 = t & 7;
    const int sr1 = (t + 256) >> 3, sj1 = (t + 256) & 7;
    const u16* gK0 = Kb + bhO + (size_t)sr0 * 64 + sj0 * 8;
    const u16* gK1 = Kb + bhO + (size_t)sr1 * 64 + sj1 * 8;
    const u16* gV0 = Vt + bhO + (size_t)sr0 * 2048 + sj0 * 8;
    const u16* gV1 = Vt + bhO + (size_t)sr1 * 2048 + sj1 * 8;

    // prologue: prefetch tile 0 into registers
    uint4 pk0 = *(const uint4*)(gK0);
    uint4 pk1 = *(const uint4*)(gK1);
    uint4 pv0 = *(const uint4*)(gV0);
    uint4 pv1 = *(const uint4*)(gV1);

    for (int kt = 0; kt <= qtB; ++kt) {
        const int k0 = kt * 64;
        __syncthreads();  // previous iteration's LDS reads done before restaging
        *(uint4*)&Ks[sr0][sj0 * 8] = pk0;
        *(uint4*)&Ks[sr1][sj1 * 8] = pk1;
        *(uint4*)&Vs[sr0][sj0 * 8] = pv0;
        *(uint4*)&Vs[sr1][sj1 * 8] = pv1;
        __syncthreads();

        if (kt < qtB) {   // issue next tile's loads now; latency hides under compute
            const size_t kn = (size_t)(k0 + 64);
            pk0 = *(const uint4*)(gK0 + kn * 64);
            pk1 = *(const uint4*)(gK1 + kn * 64);
            pv0 = *(const uint4*)(gV0 + kn);
            pv1 = *(const uint4*)(gV1 + kn);
        }

        if (kt <= qtA)    // tile A active while kt within its causal range
            attn_tile(Ks, Vs, Ps[wave], g, lr, rowqA, k0, kt == qtA, qfA0, qfA1, accA, mA, lA);
        attn_tile(Ks, Vs, Ps[wave], g, lr, rowqB, k0, kt == qtB, qfB0, qfB1, accB, mB, lB);
    }

    const int b = bh >> 4, h = bh & 15;
    #pragma unroll
    for (int di = 0; di < 4; di++)
        #pragma unroll
        for (int r = 0; r < 4; r++) {
            int sA = rowqA + g * 4 + r;
            int sB = rowqB + g * 4 + r;
            Ao[((size_t)(b * 2048 + sA)) * 1024 + h * 64 + di * 16 + lr] = f2bf(accA[di][r] / lA[r]);
            Ao[((size_t)(b * 2048 + sB)) * 1024 + h * 64 + di * 16 + lr] = f2bf(accB[di][r] / lB[r]);
        }
}

// ---------------- output projection: out = Ao @ Wp + b (fp32 out) ----------------
__global__ __launch_bounds__(256) void k_gemm_proj(const u16* __restrict__ Ao, const u16* __restrict__ Wpb,
                                                   const float* __restrict__ b_proj, float* __restrict__ out) {
    f32x4 acc[4][4];
    const int m0 = blockIdx.y * 128, n0 = blockIdx.x * 128;
    gemm128_mainloop(Ao, Wpb, m0, n0, acc);
    const int lane = threadIdx.x & 63, wave = threadIdx.x >> 6;
    const int wr = wave >> 1, wc = wave & 1, g = lane >> 4, lr = lane & 15;
    #pragma unroll
    for (int mi = 0; mi < 4; mi++)
        #pragma unroll
        for (int ni = 0; ni < 4; ni++)
            #pragma unroll
            for (int r = 0; r < 4; r++) {
                int m = m0 + wr * 64 + mi * 16 + g * 4 + r;
                int n = n0 + wc * 64 + ni * 16 + lr;
                out[(size_t)m * 1024 + n] = acc[mi][ni][r] + b_proj[n];
            }
}

extern "C" void kernel_launch(void* const* d_in, const int* in_sizes, int n_in,
                              void* d_out, int out_size, void* d_ws, size_t ws_size,
                              hipStream_t stream) {
    const float* hidden = (const float*)d_in[0];
    const float* lora   = (const float*)d_in[1];
    const float* w_attn = (const float*)d_in[2];
    const float* b_attn = (const float*)d_in[3];
    const float* w_proj = (const float*)d_in[4];
    const float* b_proj = (const float*)d_in[5];
    float* out = (float*)d_out;

    char* ws = (char*)d_ws;
    u16* Xb  = (u16*)(ws + 0x0);        // 4096x1024 bf16 (reused as Ao after QKV GEMM)
    u16* Wab = (u16*)(ws + 0x800000);   // w_attn^T  [3072][1024] bf16
    u16* Wpb = (u16*)(ws + 0xE00000);   // w_proj^T  [1024][1024] bf16
    u16* Qb  = (u16*)(ws + 0x1000000);  // [B,H,S,64] bf16 (pre-scaled by 0.125)
    u16* Kb  = (u16*)(ws + 0x1800000);  // [B,H,S,64] bf16
    u16* Vt  = (u16*)(ws + 0x2000000);  // [B,H,64,S] bf16
    u16* Ao  = Xb;                      // merged attention output [B,S,1024] bf16

    k_convert<<<1024, 256, 0, stream>>>(hidden, Xb, (2 * 2048 * 1024) / 4);
    k_tconv<<<dim3(96, 32), dim3(32, 8), 0, stream>>>(w_attn, Wab, 1024, 3072);
    k_tconv<<<dim3(32, 32), dim3(32, 8), 0, stream>>>(w_proj, Wpb, 1024, 1024);
    k_gemm_qkv<<<dim3(24, 32), 256, 0, stream>>>(Xb, Wab, lora, b_attn, Qb, Kb, Vt);
    k_attn<<<dim3(16, 32), 256, 0, stream>>>(Qb, Kb, Vt, Ao);
    k_gemm_proj<<<dim3(8, 32), 256, 0, stream>>>(Ao, Wpb, b_proj, out);
}

// Round 9
// 306.078 us; speedup vs baseline: 1.0530x; 1.0366x over previous
//
#include <hip/hip_runtime.h>
#include <hip/hip_bf16.h>
#include <cstdint>
#include <cstddef>

typedef unsigned short u16;
typedef unsigned int u32;
using f32x4  = __attribute__((ext_vector_type(4))) float;
using bf16x8 = __attribute__((ext_vector_type(8))) short;

__device__ __forceinline__ u16 f2bf(float f) {
    u32 u = __builtin_bit_cast(u32, f);
    u32 r = u + 0x7fffu + ((u >> 16) & 1u);
    return (u16)(r >> 16);
}
__device__ __forceinline__ float bf2f(u16 b) {
    u32 u = ((u32)b) << 16;
    return __builtin_bit_cast(float, u);
}

// async global->LDS, 16B per lane; LDS dest = wave-uniform base + lane*16 (linear!)
__device__ __forceinline__ void gload16(const u16* g, u16* l) {
    __builtin_amdgcn_global_load_lds(
        (const __attribute__((address_space(1))) void*)g,
        (__attribute__((address_space(3))) void*)l,
        16, 0, 0);
}

// ---------------- fp32 -> bf16 elementwise convert (vectorized) ----------------
__global__ void k_convert(const float* __restrict__ src, u16* __restrict__ dst, int n4) {
    int i = blockIdx.x * blockDim.x + threadIdx.x;
    int stride = gridDim.x * blockDim.x;
    for (; i < n4; i += stride) {
        float4 v = ((const float4*)src)[i];
        ushort4 o;
        o.x = f2bf(v.x); o.y = f2bf(v.y); o.z = f2bf(v.z); o.w = f2bf(v.w);
        ((ushort4*)dst)[i] = o;
    }
}

// ---------------- lora fp32 [4096][3072] + b_attn -> bf16 (fused bias add) ----------------
__global__ void k_lorab(const float* __restrict__ lora, const float* __restrict__ b_attn,
                        u16* __restrict__ dst, int n4) {
    int i = blockIdx.x * blockDim.x + threadIdx.x;
    int stride = gridDim.x * blockDim.x;
    for (; i < n4; i += stride) {
        float4 v = ((const float4*)lora)[i];
        float4 bz = ((const float4*)b_attn)[i % 768];   // 3072/4 float4 per row
        ushort4 o;
        o.x = f2bf(v.x + bz.x); o.y = f2bf(v.y + bz.y);
        o.z = f2bf(v.z + bz.z); o.w = f2bf(v.w + bz.w);
        ((ushort4*)dst)[i] = o;
    }
}

// ---------------- fp32 [K][N] -> bf16 [N][K] tiled transpose-convert ----------------
__global__ void k_tconv(const float* __restrict__ src, u16* __restrict__ dst, int K, int N) {
    __shared__ float tile[32][33];
    int nb = blockIdx.x * 32, kb = blockIdx.y * 32;
    int tx = threadIdx.x, ty = threadIdx.y;  // 32 x 8
    #pragma unroll
    for (int j = 0; j < 32; j += 8)
        tile[ty + j][tx] = src[(size_t)(kb + ty + j) * N + nb + tx];
    __syncthreads();
    #pragma unroll
    for (int j = 0; j < 32; j += 8)
        dst[(size_t)(nb + ty + j) * K + kb + tx] = f2bf(tile[tx][ty + j]);
}

// ---------------- shared 128x128-tile bf16 MFMA mainloop, 2-buffer + counted vmcnt ----------------
__device__ __forceinline__ void gemm128_mainloop(const u16* __restrict__ A,
                                                 const u16* __restrict__ Bt,
                                                 int m0, int n0, f32x4 (&acc)[4][4]) {
    __shared__ __align__(16) u16 As[2][128][32];
    __shared__ __align__(16) u16 Bs[2][128][32];
    const int t = threadIdx.x;
    const int lane = t & 63, wave = t >> 6;
    const int wr = wave >> 1, wc = wave & 1;
    const int g = lane >> 4, lr = lane & 15;

    #pragma unroll
    for (int mi = 0; mi < 4; mi++)
        #pragma unroll
        for (int ni = 0; ni < 4; ni++)
            acc[mi][ni] = (f32x4){0.f, 0.f, 0.f, 0.f};

    const int q0 = wave * 128 + lane;      // 16B chunk ids (linear LDS byte = q*16)
    const int q1 = q0 + 64;
    const int r0 = q0 >> 2, c0 = (q0 & 3) * 8;
    const int r1 = q1 >> 2, c1 = (q1 & 3) * 8;
    u16* lA0 = &As[0][0][0] + wave * 1024;  // wave-uniform bases
    u16* lA1 = &As[1][0][0] + wave * 1024;
    u16* lB0 = &Bs[0][0][0] + wave * 1024;
    u16* lB1 = &Bs[1][0][0] + wave * 1024;
    const u16* gA0 = A  + (size_t)(m0 + r0) * 1024 + c0;
    const u16* gA1 = A  + (size_t)(m0 + r1) * 1024 + c1;
    const u16* gB0 = Bt + (size_t)(n0 + r0) * 1024 + c0;
    const u16* gB1 = Bt + (size_t)(n0 + r1) * 1024 + c1;

    auto STAGE = [&](u16* la, u16* lb, int kt) {   // 4 global_load_lds per wave
        gload16(gA0 + kt, la);
        gload16(gA1 + kt, la + 512);
        gload16(gB0 + kt, lb);
        gload16(gB1 + kt, lb + 512);
    };
    auto COMPUTE = [&](const u16 (*Asb)[32], const u16 (*Bsb)[32]) {
        bf16x8 af[4], bfr[4];
        #pragma unroll
        for (int mi = 0; mi < 4; mi++)
            af[mi] = *(const bf16x8*)&Asb[wr * 64 + mi * 16 + lr][g * 8];
        #pragma unroll
        for (int ni = 0; ni < 4; ni++)
            bfr[ni] = *(const bf16x8*)&Bsb[wc * 64 + ni * 16 + lr][g * 8];
        #pragma unroll
        for (int mi = 0; mi < 4; mi++)
            #pragma unroll
            for (int ni = 0; ni < 4; ni++)
                acc[mi][ni] = __builtin_amdgcn_mfma_f32_16x16x32_bf16(af[mi], bfr[ni], acc[mi][ni], 0, 0, 0);
    };

    // prologue: 8 loads in flight (b0 older 4, b1 newer 4)
    STAGE(lA0, lB0, 0);
    STAGE(lA1, lB1, 32);

    for (int kt = 0; kt < 1024; kt += 64) {
        // ---- phase 0: consume b0(kt)
        asm volatile("s_waitcnt vmcnt(4)" ::: "memory");
        __builtin_amdgcn_s_barrier();
        COMPUTE(As[0], Bs[0]);
        __builtin_amdgcn_s_barrier();                  // all waves done reading b0
        asm volatile("" ::: "memory");
        if (kt + 64 < 1024) {
            STAGE(lA0, lB0, kt + 64);
            asm volatile("s_waitcnt vmcnt(4)" ::: "memory");
        } else {
            asm volatile("s_waitcnt vmcnt(0)" ::: "memory");
        }
        // ---- phase 1: consume b1(kt+32)
        __builtin_amdgcn_s_barrier();
        COMPUTE(As[1], Bs[1]);
        __builtin_amdgcn_s_barrier();
        asm volatile("" ::: "memory");
        if (kt + 96 < 1024)
            STAGE(lA1, lB1, kt + 96);
    }
}

// ---------------- QKV GEMM: C = X@W + loraB(bias folded), scatter Q(x0.125), K, V^T ----------------
// XCD swizzle: 768 blocks, xcd=bid%8; per-XCD 8 m-tiles x 12 n-tiles (~5MB working set ~ L2)
__global__ __launch_bounds__(256) void k_gemm_qkv(const u16* __restrict__ Xb, const u16* __restrict__ Wab,
                                                  const u16* __restrict__ loraB,
                                                  u16* __restrict__ Qb, u16* __restrict__ Kb, u16* __restrict__ Vt) {
    const int bid = blockIdx.y * 24 + blockIdx.x;
    const int xcd = bid & 7, k = bid >> 3;          // k in [0,96)
    const int xm = xcd & 3, xn = xcd >> 2;
    const int mt = xm * 8 + (k & 7);                // m-tile 0..31
    const int nt = xn * 12 + (k >> 3);              // n-tile 0..23
    const int m0 = mt * 128, n0 = nt * 128;

    f32x4 acc[4][4];
    gemm128_mainloop(Xb, Wab, m0, n0, acc);
    const int lane = threadIdx.x & 63, wave = threadIdx.x >> 6;
    const int wr = wave >> 1, wc = wave & 1, g = lane >> 4, lr = lane & 15;
    #pragma unroll
    for (int mi = 0; mi < 4; mi++)
        #pragma unroll
        for (int ni = 0; ni < 4; ni++)
            #pragma unroll
            for (int r = 0; r < 4; r++) {
                int m = m0 + wr * 64 + mi * 16 + g * 4 + r;
                int n = n0 + wc * 64 + ni * 16 + lr;
                float v = acc[mi][ni][r] + bf2f(loraB[(size_t)m * 3072 + n]);
                int which = n >> 10, rem = n & 1023, h = rem >> 6, hd = rem & 63;
                int b = m >> 11, s = m & 2047;
                size_t idx = ((size_t)(b * 16 + h) * 2048 + s) * 64 + hd;
                if (which == 0)      Qb[idx] = f2bf(v * 0.125f);   // fold 1/sqrt(64), exact pow2
                else if (which == 1) Kb[idx] = f2bf(v);
                else Vt[((size_t)(b * 16 + h) * 64 + hd) * 2048 + s] = f2bf(v);
            }
}

// ---------------- per-KV-tile attention compute for one wave's 16 q-rows ----------------
__device__ __forceinline__ void attn_tile(const u16 (*Ks)[72], const u16 (*Vs)[72], u16 (*Ps)[72],
                                          int g, int lr, int rowq /*q0+wave*16*/, int k0, bool diag,
                                          bf16x8 qf0, bf16x8 qf1,
                                          f32x4 (&accO)[4], float (&m_run)[4], float (&l_run)[4]) {
    f32x4 sc[4];
    #pragma unroll
    for (int ni = 0; ni < 4; ni++) {
        bf16x8 kf0 = *(const bf16x8*)&Ks[ni * 16 + lr][g * 8];
        bf16x8 kf1 = *(const bf16x8*)&Ks[ni * 16 + lr][32 + g * 8];
        f32x4 z = {0.f, 0.f, 0.f, 0.f};
        z = __builtin_amdgcn_mfma_f32_16x16x32_bf16(qf0, kf0, z, 0, 0, 0);
        z = __builtin_amdgcn_mfma_f32_16x16x32_bf16(qf1, kf1, z, 0, 0, 0);
        sc[ni] = z;
    }
    if (diag) {
        #pragma unroll
        for (int ni = 0; ni < 4; ni++)
            #pragma unroll
            for (int r = 0; r < 4; r++)
                if (k0 + ni * 16 + lr > rowq + g * 4 + r) sc[ni][r] = -INFINITY;
    }
    #pragma unroll
    for (int r = 0; r < 4; r++) {
        float mx = fmaxf(fmaxf(sc[0][r], sc[1][r]), fmaxf(sc[2][r], sc[3][r]));
        #pragma unroll
        for (int d = 1; d < 16; d <<= 1) mx = fmaxf(mx, __shfl_xor(mx, d, 64));
        float mnew = fmaxf(m_run[r], mx);
        float fsc = __expf(m_run[r] - mnew);
        float ls = 0.f;
        #pragma unroll
        for (int ni = 0; ni < 4; ni++) {
            float p = __expf(sc[ni][r] - mnew);
            sc[ni][r] = p;
            ls += p;
        }
        #pragma unroll
        for (int d = 1; d < 16; d <<= 1) ls += __shfl_xor(ls, d, 64);
        #pragma unroll
        for (int di = 0; di < 4; di++) accO[di][r] *= fsc;
        m_run[r] = mnew;
        l_run[r] = l_run[r] * fsc + ls;
    }
    #pragma unroll
    for (int ni = 0; ni < 4; ni++)
        #pragma unroll
        for (int r = 0; r < 4; r++)
            Ps[g * 4 + r][ni * 16 + lr] = f2bf(sc[ni][r]);
    #pragma unroll
    for (int e = 0; e < 2; e++) {
        bf16x8 pa = *(const bf16x8*)&Ps[lr][e * 32 + g * 8];
        #pragma unroll
        for (int di = 0; di < 4; di++) {
            bf16x8 vb = *(const bf16x8*)&Vs[di * 16 + lr][e * 32 + g * 8];
            accO[di] = __builtin_amdgcn_mfma_f32_16x16x32_bf16(pa, vb, accO[di], 0, 0, 0);
        }
    }
}

// ---------------- causal flash attention: paired q-tiles {i, 31-i} per block ----------------
__global__ __launch_bounds__(256) void k_attn(const u16* __restrict__ Qb, const u16* __restrict__ Kb,
                                              const u16* __restrict__ Vt, u16* __restrict__ Ao) {
    __shared__ __align__(16) u16 Ks[64][72];
    __shared__ __align__(16) u16 Vs[64][72];
    __shared__ __align__(16) u16 Ps[4][16][72];
    const int i = blockIdx.x, bh = blockIdx.y;
    const int qtA = i, qtB = 31 - i;
    const int t = threadIdx.x, wave = t >> 6, lane = t & 63;
    const int g = lane >> 4, lr = lane & 15;
    const size_t bhO = (size_t)bh * (2048 * 64);
    const int q0A = qtA * 64, q0B = qtB * 64;
    const int rowqA = q0A + wave * 16, rowqB = q0B + wave * 16;

    bf16x8 qfA0 = *(const bf16x8*)(Qb + bhO + (size_t)(rowqA + lr) * 64 + g * 8);
    bf16x8 qfA1 = *(const bf16x8*)(Qb + bhO + (size_t)(rowqA + lr) * 64 + 32 + g * 8);
    bf16x8 qfB0 = *(const bf16x8*)(Qb + bhO + (size_t)(rowqB + lr) * 64 + g * 8);
    bf16x8 qfB1 = *(const bf16x8*)(Qb + bhO + (size_t)(rowqB + lr) * 64 + 32 + g * 8);

    f32x4 accA[4], accB[4];
    float mA[4], lA[4], mB[4], lB[4];
    #pragma unroll
    for (int x = 0; x < 4; x++) {
        accA[x] = (f32x4){0.f,0.f,0.f,0.f}; accB[x] = (f32x4){0.f,0.f,0.f,0.f};
        mA[x] = -INFINITY; lA[x] = 0.f; mB[x] = -INFINITY; lB[x] = 0.f;
    }

    const int sr0 = t >> 3,         sj0 = t & 7;
    const int sr1 = (t + 256) >> 3, sj1 = (t + 256) & 7;
    const u16* gK0 = Kb + bhO + (size_t)sr0 * 64 + sj0 * 8;
    const u16* gK1 = Kb + bhO + (size_t)sr1 * 64 + sj1 * 8;
    const u16* gV0 = Vt + bhO + (size_t)sr0 * 2048 + sj0 * 8;
    const u16* gV1 = Vt + bhO + (size_t)sr1 * 2048 + sj1 * 8;

    uint4 pk0 = *(const uint4*)(gK0);
    uint4 pk1 = *(const uint4*)(gK1);
    uint4 pv0 = *(const uint4*)(gV0);
    uint4 pv1 = *(const uint4*)(gV1);

    for (int kt = 0; kt <= qtB; ++kt) {
        const int k0 = kt * 64;
        __syncthreads();
        *(uint4*)&Ks[sr0][sj0 * 8] = pk0;
        *(uint4*)&Ks[sr1][sj1 * 8] = pk1;
        *(uint4*)&Vs[sr0][sj0 * 8] = pv0;
        *(uint4*)&Vs[sr1][sj1 * 8] = pv1;
        __syncthreads();

        if (kt < qtB) {
            const size_t kn = (size_t)(k0 + 64);
            pk0 = *(const uint4*)(gK0 + kn * 64);
            pk1 = *(const uint4*)(gK1 + kn * 64);
            pv0 = *(const uint4*)(gV0 + kn);
            pv1 = *(const uint4*)(gV1 + kn);
        }

        if (kt <= qtA)
            attn_tile(Ks, Vs, Ps[wave], g, lr, rowqA, k0, kt == qtA, qfA0, qfA1, accA, mA, lA);
        attn_tile(Ks, Vs, Ps[wave], g, lr, rowqB, k0, kt == qtB, qfB0, qfB1, accB, mB, lB);
    }

    const int b = bh >> 4, h = bh & 15;
    #pragma unroll
    for (int di = 0; di < 4; di++)
        #pragma unroll
        for (int r = 0; r < 4; r++) {
            int sA = rowqA + g * 4 + r;
            int sB = rowqB + g * 4 + r;
            Ao[((size_t)(b * 2048 + sA)) * 1024 + h * 64 + di * 16 + lr] = f2bf(accA[di][r] / lA[r]);
            Ao[((size_t)(b * 2048 + sB)) * 1024 + h * 64 + di * 16 + lr] = f2bf(accB[di][r] / lB[r]);
        }
}

// ---------------- output projection: out = Ao @ Wp + b (fp32 out), XCD-swizzled ----------------
__global__ __launch_bounds__(256) void k_gemm_proj(const u16* __restrict__ Ao, const u16* __restrict__ Wpb,
                                                   const float* __restrict__ b_proj, float* __restrict__ out) {
    const int bid = blockIdx.y * 8 + blockIdx.x;    // 256 blocks
    const int xcd = bid & 7, k = bid >> 3;          // k in [0,32)
    const int xm = xcd & 3, xn = xcd >> 2;
    const int mt = xm * 8 + (k & 7);                // m-tile 0..31
    const int nt = xn * 4 + (k >> 3);               // n-tile 0..7
    const int m0 = mt * 128, n0 = nt * 128;

    f32x4 acc[4][4];
    gemm128_mainloop(Ao, Wpb, m0, n0, acc);
    const int lane = threadIdx.x & 63, wave = threadIdx.x >> 6;
    const int wr = wave >> 1, wc = wave & 1, g = lane >> 4, lr = lane & 15;
    #pragma unroll
    for (int mi = 0; mi < 4; mi++)
        #pragma unroll
        for (int ni = 0; ni < 4; ni++)
            #pragma unroll
            for (int r = 0; r < 4; r++) {
                int m = m0 + wr * 64 + mi * 16 + g * 4 + r;
                int n = n0 + wc * 64 + ni * 16 + lr;
                out[(size_t)m * 1024 + n] = acc[mi][ni][r] + b_proj[n];
            }
}

extern "C" void kernel_launch(void* const* d_in, const int* in_sizes, int n_in,
                              void* d_out, int out_size, void* d_ws, size_t ws_size,
                              hipStream_t stream) {
    const float* hidden = (const float*)d_in[0];
    const float* lora   = (const float*)d_in[1];
    const float* w_attn = (const float*)d_in[2];
    const float* b_attn = (const float*)d_in[3];
    const float* w_proj = (const float*)d_in[4];
    const float* b_proj = (const float*)d_in[5];
    float* out = (float*)d_out;

    char* ws = (char*)d_ws;
    u16* Xb   = (u16*)(ws + 0x0);        // 4096x1024 bf16 (reused as Ao after QKV GEMM)
    u16* Wab  = (u16*)(ws + 0x800000);   // w_attn^T  [3072][1024] bf16
    u16* Wpb  = (u16*)(ws + 0xE00000);   // w_proj^T  [1024][1024] bf16
    u16* Qb   = (u16*)(ws + 0x1000000);  // [B,H,S,64] bf16 (pre-scaled by 0.125)
    u16* Kb   = (u16*)(ws + 0x1800000);  // [B,H,S,64] bf16
    u16* Vt   = (u16*)(ws + 0x2000000);  // [B,H,64,S] bf16
    u16* lorB = (u16*)(ws + 0x2800000);  // [4096][3072] bf16 (lora + b_attn fused)
    u16* Ao   = Xb;                      // merged attention output [B,S,1024] bf16

    k_convert<<<1024, 256, 0, stream>>>(hidden, Xb, (2 * 2048 * 1024) / 4);
    k_lorab<<<2048, 256, 0, stream>>>(lora, b_attn, lorB, (4096 * 3072) / 4);
    k_tconv<<<dim3(96, 32), dim3(32, 8), 0, stream>>>(w_attn, Wab, 1024, 3072);
    k_tconv<<<dim3(32, 32), dim3(32, 8), 0, stream>>>(w_proj, Wpb, 1024, 1024);
    k_gemm_qkv<<<dim3(24, 32), 256, 0, stream>>>(Xb, Wab, lorB, Qb, Kb, Vt);
    k_attn<<<dim3(16, 32), 256, 0, stream>>>(Qb, Kb, Vt, Ao);
    k_gemm_proj<<<dim3(8, 32), 256, 0, stream>>>(Ao, Wpb, b_proj, out);
}

// Round 10
// 278.539 us; speedup vs baseline: 1.1571x; 1.0989x over previous
//
#include <hip/hip_runtime.h>
#include <hip/hip_bf16.h>
#include <cstdint>
#include <cstddef>

typedef unsigned short u16;
typedef unsigned int u32;
using f32x4  = __attribute__((ext_vector_type(4))) float;
using bf16x8 = __attribute__((ext_vector_type(8))) short;

__device__ __forceinline__ u16 f2bf(float f) {
    u32 u = __builtin_bit_cast(u32, f);
    u32 r = u + 0x7fffu + ((u >> 16) & 1u);
    return (u16)(r >> 16);
}
__device__ __forceinline__ float bf2f(u16 b) {
    u32 u = ((u32)b) << 16;
    return __builtin_bit_cast(float, u);
}

// async global->LDS, 16B per lane; LDS dest = wave-uniform base + lane*16 (linear!)
__device__ __forceinline__ void gload16(const u16* g, u16* l) {
    __builtin_amdgcn_global_load_lds(
        (const __attribute__((address_space(1))) void*)g,
        (__attribute__((address_space(3))) void*)l,
        16, 0, 0);
}

// ---------------- fp32 -> bf16 elementwise convert (vectorized) ----------------
__global__ void k_convert(const float* __restrict__ src, u16* __restrict__ dst, int n4) {
    int i = blockIdx.x * blockDim.x + threadIdx.x;
    int stride = gridDim.x * blockDim.x;
    for (; i < n4; i += stride) {
        float4 v = ((const float4*)src)[i];
        ushort4 o;
        o.x = f2bf(v.x); o.y = f2bf(v.y); o.z = f2bf(v.z); o.w = f2bf(v.w);
        ((ushort4*)dst)[i] = o;
    }
}

// ---------------- lora fp32 [4096][3072] + b_attn -> bf16 (fused bias add) ----------------
__global__ void k_lorab(const float* __restrict__ lora, const float* __restrict__ b_attn,
                        u16* __restrict__ dst, int n4) {
    int i = blockIdx.x * blockDim.x + threadIdx.x;
    int stride = gridDim.x * blockDim.x;
    for (; i < n4; i += stride) {
        float4 v = ((const float4*)lora)[i];
        float4 bz = ((const float4*)b_attn)[i % 768];   // 3072/4 float4 per row
        ushort4 o;
        o.x = f2bf(v.x + bz.x); o.y = f2bf(v.y + bz.y);
        o.z = f2bf(v.z + bz.z); o.w = f2bf(v.w + bz.w);
        ((ushort4*)dst)[i] = o;
    }
}

// ---------------- fp32 [K][N] -> bf16 [N][K] tiled transpose-convert ----------------
__global__ void k_tconv(const float* __restrict__ src, u16* __restrict__ dst, int K, int N) {
    __shared__ float tile[32][33];
    int nb = blockIdx.x * 32, kb = blockIdx.y * 32;
    int tx = threadIdx.x, ty = threadIdx.y;  // 32 x 8
    #pragma unroll
    for (int j = 0; j < 32; j += 8)
        tile[ty + j][tx] = src[(size_t)(kb + ty + j) * N + nb + tx];
    __syncthreads();
    #pragma unroll
    for (int j = 0; j < 32; j += 8)
        dst[(size_t)(nb + ty + j) * K + kb + tx] = f2bf(tile[tx][ty + j]);
}

// ---------------- shared 128x128-tile bf16 MFMA mainloop, 2-buffer + counted vmcnt ----------------
__device__ __forceinline__ void gemm128_mainloop(const u16* __restrict__ A,
                                                 const u16* __restrict__ Bt,
                                                 int m0, int n0, f32x4 (&acc)[4][4]) {
    __shared__ __align__(16) u16 As[2][128][32];
    __shared__ __align__(16) u16 Bs[2][128][32];
    const int t = threadIdx.x;
    const int lane = t & 63, wave = t >> 6;
    const int wr = wave >> 1, wc = wave & 1;
    const int g = lane >> 4, lr = lane & 15;

    #pragma unroll
    for (int mi = 0; mi < 4; mi++)
        #pragma unroll
        for (int ni = 0; ni < 4; ni++)
            acc[mi][ni] = (f32x4){0.f, 0.f, 0.f, 0.f};

    const int q0 = wave * 128 + lane;      // 16B chunk ids (linear LDS byte = q*16)
    const int q1 = q0 + 64;
    const int r0 = q0 >> 2, c0 = (q0 & 3) * 8;
    const int r1 = q1 >> 2, c1 = (q1 & 3) * 8;
    u16* lA0 = &As[0][0][0] + wave * 1024;  // wave-uniform bases
    u16* lA1 = &As[1][0][0] + wave * 1024;
    u16* lB0 = &Bs[0][0][0] + wave * 1024;
    u16* lB1 = &Bs[1][0][0] + wave * 1024;
    const u16* gA0 = A  + (size_t)(m0 + r0) * 1024 + c0;
    const u16* gA1 = A  + (size_t)(m0 + r1) * 1024 + c1;
    const u16* gB0 = Bt + (size_t)(n0 + r0) * 1024 + c0;
    const u16* gB1 = Bt + (size_t)(n0 + r1) * 1024 + c1;

    auto STAGE = [&](u16* la, u16* lb, int kt) {   // 4 global_load_lds per wave
        gload16(gA0 + kt, la);
        gload16(gA1 + kt, la + 512);
        gload16(gB0 + kt, lb);
        gload16(gB1 + kt, lb + 512);
    };
    auto COMPUTE = [&](const u16 (*Asb)[32], const u16 (*Bsb)[32]) {
        bf16x8 af[4], bfr[4];
        #pragma unroll
        for (int mi = 0; mi < 4; mi++)
            af[mi] = *(const bf16x8*)&Asb[wr * 64 + mi * 16 + lr][g * 8];
        #pragma unroll
        for (int ni = 0; ni < 4; ni++)
            bfr[ni] = *(const bf16x8*)&Bsb[wc * 64 + ni * 16 + lr][g * 8];
        #pragma unroll
        for (int mi = 0; mi < 4; mi++)
            #pragma unroll
            for (int ni = 0; ni < 4; ni++)
                acc[mi][ni] = __builtin_amdgcn_mfma_f32_16x16x32_bf16(af[mi], bfr[ni], acc[mi][ni], 0, 0, 0);
    };

    // prologue: 8 loads in flight (b0 older 4, b1 newer 4)
    STAGE(lA0, lB0, 0);
    STAGE(lA1, lB1, 32);

    for (int kt = 0; kt < 1024; kt += 64) {
        // ---- phase 0: consume b0(kt)
        asm volatile("s_waitcnt vmcnt(4)" ::: "memory");
        __builtin_amdgcn_s_barrier();
        COMPUTE(As[0], Bs[0]);
        __builtin_amdgcn_s_barrier();                  // all waves done reading b0
        asm volatile("" ::: "memory");
        if (kt + 64 < 1024) {
            STAGE(lA0, lB0, kt + 64);
            asm volatile("s_waitcnt vmcnt(4)" ::: "memory");
        } else {
            asm volatile("s_waitcnt vmcnt(0)" ::: "memory");
        }
        // ---- phase 1: consume b1(kt+32)
        __builtin_amdgcn_s_barrier();
        COMPUTE(As[1], Bs[1]);
        __builtin_amdgcn_s_barrier();
        asm volatile("" ::: "memory");
        if (kt + 96 < 1024)
            STAGE(lA1, lB1, kt + 96);
    }
}

// ---------------- QKV GEMM: C = X@W + loraB (in-place into loraB buffer), Q cols pre-scaled ----------------
// Clean epilogue: single destination, no layout scatter (that moved to k_scatter).
__global__ __launch_bounds__(256) void k_gemm_qkv(const u16* __restrict__ Xb, const u16* __restrict__ Wab,
                                                  u16* __restrict__ C /* = loraB, in-place */) {
    const int bid = blockIdx.y * 24 + blockIdx.x;
    const int xcd = bid & 7, k = bid >> 3;          // k in [0,96)
    const int xm = xcd & 3, xn = xcd >> 2;
    const int mt = xm * 8 + (k & 7);                // m-tile 0..31
    const int nt = xn * 12 + (k >> 3);              // n-tile 0..23
    const int m0 = mt * 128, n0 = nt * 128;

    f32x4 acc[4][4];
    gemm128_mainloop(Xb, Wab, m0, n0, acc);
    const int lane = threadIdx.x & 63, wave = threadIdx.x >> 6;
    const int wr = wave >> 1, wc = wave & 1, g = lane >> 4, lr = lane & 15;
    const float qs = (n0 < 1024) ? 0.125f : 1.0f;   // fold 1/sqrt(64) into Q columns (block-uniform)
    #pragma unroll
    for (int mi = 0; mi < 4; mi++)
        #pragma unroll
        for (int ni = 0; ni < 4; ni++)
            #pragma unroll
            for (int r = 0; r < 4; r++) {
                int m = m0 + wr * 64 + mi * 16 + g * 4 + r;
                int n = n0 + wc * 64 + ni * 16 + lr;
                size_t idx = (size_t)m * 3072 + n;
                float v = acc[mi][ni][r] + bf2f(C[idx]);   // read-modify-write, disjoint per thread
                C[idx] = f2bf(v * qs);
            }
}

// ---------------- scatter/reshape: C[B*S][3072] -> Qb/Kb [bh][s][64], Vt [bh][64][s] ----------------
// All global reads/writes 16B-coalesced; V transposed through LDS.
__global__ __launch_bounds__(256) void k_scatter(const u16* __restrict__ C,
                                                 u16* __restrict__ Qb, u16* __restrict__ Kb,
                                                 u16* __restrict__ Vt) {
    __shared__ u16 vt[32][72];
    const int st = blockIdx.x, bh = blockIdx.y;
    const int b = bh >> 4, h = bh & 15;
    const int s0 = st * 32;
    const int tid = threadIdx.x;
    const int i = tid >> 3, j = tid & 7;            // i: s-row 0..31, j: 16B chunk 0..7
    const size_t crow = (size_t)(b * 2048 + s0 + i) * 3072 + h * 64 + j * 8;
    const size_t orow = ((size_t)bh * 2048 + s0 + i) * 64 + j * 8;

    uint4 q = *(const uint4*)(C + crow);            // Q block (already scaled)
    *(uint4*)(Qb + orow) = q;
    uint4 kk = *(const uint4*)(C + crow + 1024);    // K block
    *(uint4*)(Kb + orow) = kk;
    uint4 vv = *(const uint4*)(C + crow + 2048);    // V block -> LDS tile
    *(uint4*)(&vt[i][j * 8]) = vv;
    __syncthreads();
    const int hd = tid >> 2, jj = tid & 3;          // hd 0..63, jj: 8-s chunk 0..3
    u16 tmp[8];
    #pragma unroll
    for (int x = 0; x < 8; x++) tmp[x] = vt[jj * 8 + x][hd];
    *(uint4*)(Vt + ((size_t)bh * 64 + hd) * 2048 + s0 + jj * 8) = *(uint4*)tmp;
}

// ---------------- per-KV-tile attention compute for one wave's 16 q-rows ----------------
__device__ __forceinline__ void attn_tile(const u16 (*Ks)[72], const u16 (*Vs)[72], u16 (*Ps)[72],
                                          int g, int lr, int rowq /*q0+wave*16*/, int k0, bool diag,
                                          bf16x8 qf0, bf16x8 qf1,
                                          f32x4 (&accO)[4], float (&m_run)[4], float (&l_run)[4]) {
    f32x4 sc[4];
    #pragma unroll
    for (int ni = 0; ni < 4; ni++) {
        bf16x8 kf0 = *(const bf16x8*)&Ks[ni * 16 + lr][g * 8];
        bf16x8 kf1 = *(const bf16x8*)&Ks[ni * 16 + lr][32 + g * 8];
        f32x4 z = {0.f, 0.f, 0.f, 0.f};
        z = __builtin_amdgcn_mfma_f32_16x16x32_bf16(qf0, kf0, z, 0, 0, 0);
        z = __builtin_amdgcn_mfma_f32_16x16x32_bf16(qf1, kf1, z, 0, 0, 0);
        sc[ni] = z;
    }
    if (diag) {
        #pragma unroll
        for (int ni = 0; ni < 4; ni++)
            #pragma unroll
            for (int r = 0; r < 4; r++)
                if (k0 + ni * 16 + lr > rowq + g * 4 + r) sc[ni][r] = -INFINITY;
    }
    #pragma unroll
    for (int r = 0; r < 4; r++) {
        float mx = fmaxf(fmaxf(sc[0][r], sc[1][r]), fmaxf(sc[2][r], sc[3][r]));
        #pragma unroll
        for (int d = 1; d < 16; d <<= 1) mx = fmaxf(mx, __shfl_xor(mx, d, 64));
        float mnew = fmaxf(m_run[r], mx);
        float fsc = __expf(m_run[r] - mnew);
        float ls = 0.f;
        #pragma unroll
        for (int ni = 0; ni < 4; ni++) {
            float p = __expf(sc[ni][r] - mnew);
            sc[ni][r] = p;
            ls += p;
        }
        #pragma unroll
        for (int d = 1; d < 16; d <<= 1) ls += __shfl_xor(ls, d, 64);
        #pragma unroll
        for (int di = 0; di < 4; di++) accO[di][r] *= fsc;
        m_run[r] = mnew;
        l_run[r] = l_run[r] * fsc + ls;
    }
    #pragma unroll
    for (int ni = 0; ni < 4; ni++)
        #pragma unroll
        for (int r = 0; r < 4; r++)
            Ps[g * 4 + r][ni * 16 + lr] = f2bf(sc[ni][r]);
    #pragma unroll
    for (int e = 0; e < 2; e++) {
        bf16x8 pa = *(const bf16x8*)&Ps[lr][e * 32 + g * 8];
        #pragma unroll
        for (int di = 0; di < 4; di++) {
            bf16x8 vb = *(const bf16x8*)&Vs[di * 16 + lr][e * 32 + g * 8];
            accO[di] = __builtin_amdgcn_mfma_f32_16x16x32_bf16(pa, vb, accO[di], 0, 0, 0);
        }
    }
}

// ---------------- causal flash attention: paired q-tiles {i, 31-i} per block ----------------
__global__ __launch_bounds__(256) void k_attn(const u16* __restrict__ Qb, const u16* __restrict__ Kb,
                                              const u16* __restrict__ Vt, u16* __restrict__ Ao) {
    __shared__ __align__(16) u16 Ks[64][72];
    __shared__ __align__(16) u16 Vs[64][72];
    __shared__ __align__(16) u16 Ps[4][16][72];
    const int i = blockIdx.x, bh = blockIdx.y;
    const int qtA = i, qtB = 31 - i;
    const int t = threadIdx.x, wave = t >> 6, lane = t & 63;
    const int g = lane >> 4, lr = lane & 15;
    const size_t bhO = (size_t)bh * (2048 * 64);
    const int q0A = qtA * 64, q0B = qtB * 64;
    const int rowqA = q0A + wave * 16, rowqB = q0B + wave * 16;

    bf16x8 qfA0 = *(const bf16x8*)(Qb + bhO + (size_t)(rowqA + lr) * 64 + g * 8);
    bf16x8 qfA1 = *(const bf16x8*)(Qb + bhO + (size_t)(rowqA + lr) * 64 + 32 + g * 8);
    bf16x8 qfB0 = *(const bf16x8*)(Qb + bhO + (size_t)(rowqB + lr) * 64 + g * 8);
    bf16x8 qfB1 = *(const bf16x8*)(Qb + bhO + (size_t)(rowqB + lr) * 64 + 32 + g * 8);

    f32x4 accA[4], accB[4];
    float mA[4], lA[4], mB[4], lB[4];
    #pragma unroll
    for (int x = 0; x < 4; x++) {
        accA[x] = (f32x4){0.f,0.f,0.f,0.f}; accB[x] = (f32x4){0.f,0.f,0.f,0.f};
        mA[x] = -INFINITY; lA[x] = 0.f; mB[x] = -INFINITY; lB[x] = 0.f;
    }

    const int sr0 = t >> 3,         sj0 = t & 7;
    const int sr1 = (t + 256) >> 3, sj1 = (t + 256) & 7;
    const u16* gK0 = Kb + bhO + (size_t)sr0 * 64 + sj0 * 8;
    const u16* gK1 = Kb + bhO + (size_t)sr1 * 64 + sj1 * 8;
    const u16* gV0 = Vt + bhO + (size_t)sr0 * 2048 + sj0 * 8;
    const u16* gV1 = Vt + bhO + (size_t)sr1 * 2048 + sj1 * 8;

    uint4 pk0 = *(const uint4*)(gK0);
    uint4 pk1 = *(const uint4*)(gK1);
    uint4 pv0 = *(const uint4*)(gV0);
    uint4 pv1 = *(const uint4*)(gV1);

    for (int kt = 0; kt <= qtB; ++kt) {
        const int k0 = kt * 64;
        __syncthreads();
        *(uint4*)&Ks[sr0][sj0 * 8] = pk0;
        *(uint4*)&Ks[sr1][sj1 * 8] = pk1;
        *(uint4*)&Vs[sr0][sj0 * 8] = pv0;
        *(uint4*)&Vs[sr1][sj1 * 8] = pv1;
        __syncthreads();

        if (kt < qtB) {
            const size_t kn = (size_t)(k0 + 64);
            pk0 = *(const uint4*)(gK0 + kn * 64);
            pk1 = *(const uint4*)(gK1 + kn * 64);
            pv0 = *(const uint4*)(gV0 + kn);
            pv1 = *(const uint4*)(gV1 + kn);
        }

        if (kt <= qtA)
            attn_tile(Ks, Vs, Ps[wave], g, lr, rowqA, k0, kt == qtA, qfA0, qfA1, accA, mA, lA);
        attn_tile(Ks, Vs, Ps[wave], g, lr, rowqB, k0, kt == qtB, qfB0, qfB1, accB, mB, lB);
    }

    const int b = bh >> 4, h = bh & 15;
    #pragma unroll
    for (int di = 0; di < 4; di++)
        #pragma unroll
        for (int r = 0; r < 4; r++) {
            int sA = rowqA + g * 4 + r;
            int sB = rowqB + g * 4 + r;
            Ao[((size_t)(b * 2048 + sA)) * 1024 + h * 64 + di * 16 + lr] = f2bf(accA[di][r] / lA[r]);
            Ao[((size_t)(b * 2048 + sB)) * 1024 + h * 64 + di * 16 + lr] = f2bf(accB[di][r] / lB[r]);
        }
}

// ---------------- output projection: out = Ao @ Wp + b (fp32 out), XCD-swizzled ----------------
__global__ __launch_bounds__(256) void k_gemm_proj(const u16* __restrict__ Ao, const u16* __restrict__ Wpb,
                                                   const float* __restrict__ b_proj, float* __restrict__ out) {
    const int bid = blockIdx.y * 8 + blockIdx.x;    // 256 blocks
    const int xcd = bid & 7, k = bid >> 3;          // k in [0,32)
    const int xm = xcd & 3, xn = xcd >> 2;
    const int mt = xm * 8 + (k & 7);                // m-tile 0..31
    const int nt = xn * 4 + (k >> 3);               // n-tile 0..7
    const int m0 = mt * 128, n0 = nt * 128;

    f32x4 acc[4][4];
    gemm128_mainloop(Ao, Wpb, m0, n0, acc);
    const int lane = threadIdx.x & 63, wave = threadIdx.x >> 6;
    const int wr = wave >> 1, wc = wave & 1, g = lane >> 4, lr = lane & 15;
    #pragma unroll
    for (int mi = 0; mi < 4; mi++)
        #pragma unroll
        for (int ni = 0; ni < 4; ni++)
            #pragma unroll
            for (int r = 0; r < 4; r++) {
                int m = m0 + wr * 64 + mi * 16 + g * 4 + r;
                int n = n0 + wc * 64 + ni * 16 + lr;
                out[(size_t)m * 1024 + n] = acc[mi][ni][r] + b_proj[n];
            }
}

extern "C" void kernel_launch(void* const* d_in, const int* in_sizes, int n_in,
                              void* d_out, int out_size, void* d_ws, size_t ws_size,
                              hipStream_t stream) {
    const float* hidden = (const float*)d_in[0];
    const float* lora   = (const float*)d_in[1];
    const float* w_attn = (const float*)d_in[2];
    const float* b_attn = (const float*)d_in[3];
    const float* w_proj = (const float*)d_in[4];
    const float* b_proj = (const float*)d_in[5];
    float* out = (float*)d_out;

    char* ws = (char*)d_ws;
    u16* Xb   = (u16*)(ws + 0x0);        // 4096x1024 bf16 (reused as Ao after QKV GEMM)
    u16* Wab  = (u16*)(ws + 0x800000);   // w_attn^T  [3072][1024] bf16
    u16* Wpb  = (u16*)(ws + 0xE00000);   // w_proj^T  [1024][1024] bf16
    u16* Qb   = (u16*)(ws + 0x1000000);  // [B,H,S,64] bf16 (pre-scaled by 0.125)
    u16* Kb   = (u16*)(ws + 0x1800000);  // [B,H,S,64] bf16
    u16* Vt   = (u16*)(ws + 0x2000000);  // [B,H,64,S] bf16
    u16* lorB = (u16*)(ws + 0x2800000);  // [4096][3072] bf16: lora+b_attn, then in-place QKV result C
    u16* Ao   = Xb;                      // merged attention output [B,S,1024] bf16

    k_convert<<<1024, 256, 0, stream>>>(hidden, Xb, (2 * 2048 * 1024) / 4);
    k_lorab<<<2048, 256, 0, stream>>>(lora, b_attn, lorB, (4096 * 3072) / 4);
    k_tconv<<<dim3(96, 32), dim3(32, 8), 0, stream>>>(w_attn, Wab, 1024, 3072);
    k_tconv<<<dim3(32, 32), dim3(32, 8), 0, stream>>>(w_proj, Wpb, 1024, 1024);
    k_gemm_qkv<<<dim3(24, 32), 256, 0, stream>>>(Xb, Wab, lorB);
    k_scatter<<<dim3(64, 32), 256, 0, stream>>>(lorB, Qb, Kb, Vt);
    k_attn<<<dim3(16, 32), 256, 0, stream>>>(Qb, Kb, Vt, Ao);
    k_gemm_proj<<<dim3(8, 32), 256, 0, stream>>>(Ao, Wpb, b_proj, out);
}